// Round 10
// baseline (239.825 us; speedup 1.0000x reference)
//
#include <hip/hip_runtime.h>
#include <stdint.h>

// Top-K (K=64) per row of [4096, 32768] f32, relu'd, scattered into zeros.
//
// Round-10: TWO-KERNEL SPLIT with the lean reader.
//   R9 null result exonerated hot-loop instruction mass; the fused
//   read+write stream is pinned at ~4.8 TB/s vs 6.3 TB/s per pure stream.
//   R7's split was contaminated by the old atomic-heavy select (~198 us);
//   the lean capture loop has never run as a pure read stream.
//  - Kernel A (select): pure-read stream + float4-granularity capture
//    (2 v_max + 1 ds_write_b32 per group), compaction via 16B global
//    re-reads (L2-hot), exact 4x8-bit radix select, lowest-index-first
//    tie-break (matches jax.lax.top_k). Winners ({pos,bits} + count) go to
//    d_ws (~2 MB), NOT to out.
//  - Kernel B (fill+scatter): one block per row: nontemporal zero stores
//    for the whole row (pure write stream), __syncthreads (drains vmcnt),
//    then <=64 scatter stores from ws. Same-block ordering -> no race.
//  - Fallback A-side (slot/list overflow, M < 64; statistically never):
//    exact 32-bit radix over global re-reads -> winners to ws (relu'd).
//  - Host-side: if ws_size < needed, launch the proven R9 fused kernel.

#define LROW   32768
#define ROWS_MAX 65536
#define NT     256
#define NWAVE  (NT / 64)            // 4
#define ITERS  (LROW / (NT * 4))    // 32
#define KSEL   64u
#define CAP    1024u                // expanded candidate list capacity
#define NSLOT  8                    // group slots per thread (+1 trash)
#define FCUT   2.6f                 // candidate threshold (value space)

typedef float vf4 __attribute__((ext_vector_type(4)));

// float bits -> order-preserving uint (used only in fallbacks)
__device__ __forceinline__ uint32_t f2o(uint32_t b) {
    return b ^ (uint32_t)(((int32_t)b >> 31) | 0x80000000u);
}
__device__ __forceinline__ float o2f(uint32_t u) {
    uint32_t b = (u & 0x80000000u) ? (u ^ 0x80000000u) : ~u;
    return __uint_as_float(b);
}

// Wave 0 scans hist[nb-1..0] from the top; finds bucket b* with
// cum_before < need <= cum_before + hist[b*]; writes {b*, cum_before, hist[b*]}
// to ctrl[0..2]. Caller syncs before (hist ready) and after (result visible).
__device__ __forceinline__ void wave0_select(uint32_t* ctrl, const uint32_t* hist,
                                             int nb, uint32_t need,
                                             int tid, int lane)
{
    if (tid < 64) {
        uint32_t cum = 0;
        int done = 0;
        for (int base = nb; base > 0 && !done; base -= 64) {
            uint32_t c = hist[base - 1 - lane];   // lane 0 = highest bucket
            uint32_t inc = c;
            #pragma unroll
            for (int off = 1; off < 64; off <<= 1) {
                uint32_t t = __shfl_up(inc, off);
                if (lane >= off) inc += t;
            }
            uint32_t tot = __shfl(inc, 63);
            uint32_t pre = inc - c;
            bool hit = (cum + pre < need) && (cum + pre + c >= need);
            if (hit) {
                ctrl[0] = (uint32_t)(base - 1 - lane);
                ctrl[1] = cum + pre;
                ctrl[2] = c;
            }
            done = (__ballot(hit) != 0ull);
            cum += tot;
        }
    }
}

// Lean group-granularity capture: 2 v_max + cmp/add + min + addr + ds_write_b32.
__device__ __forceinline__ void scan4g(const float4& v, int p4, int tid,
                                       uint32_t* pool, uint32_t& c)
{
    float m = fmaxf(fmaxf(v.x, v.y), fmaxf(v.z, v.w));
    uint32_t s = (c > (uint32_t)NSLOT) ? (uint32_t)NSLOT : c;
    pool[s * NT + tid] = (uint32_t)p4;
    c += (m >= FCUT) ? 1u : 0u;
}

// ============================ Kernel A: select ============================
__global__ __launch_bounds__(NT, 8) void select_kernel(
    const float* __restrict__ x, uint2* __restrict__ wswin,
    uint32_t* __restrict__ wscnt)
{
    __shared__ uint32_t pool[(NSLOT + 1) * NT];   // 9 KiB: captured group idxs
    __shared__ uint2    list[CAP];                // 8 KiB: expanded {key,pos}
    __shared__ uint32_t hist[256];
    __shared__ uint32_t ctrl[64];   // [0..2] sel, [3] cnt, [8] ovf, [10] ws cnt, [16..] wave sums

    const int tid  = threadIdx.x;
    const int lane = tid & 63;
    const int wid  = tid >> 6;
    const uint32_t row = blockIdx.x;
    const size_t rowoff = (size_t)row * LROW;
    const float4* __restrict__ xin = (const float4*)(x + rowoff);

    if (tid == 0) { ctrl[3] = 0u; ctrl[8] = 0u; ctrl[10] = 0u; }
    __syncthreads();

    // ---- Phase 0: PURE READ stream + lean group capture ----
    uint32_t c = 0;
    for (int j = 0; j < ITERS; j += 4) {
        int p0 = (j + 0) * NT + tid;
        int p1 = (j + 1) * NT + tid;
        int p2 = (j + 2) * NT + tid;
        int p3 = (j + 3) * NT + tid;
        float4 v0 = xin[p0];
        float4 v1 = xin[p1];
        float4 v2 = xin[p2];
        float4 v3 = xin[p3];
        scan4g(v0, p0, tid, pool, c);
        scan4g(v1, p1, tid, pool, c);
        scan4g(v2, p2, tid, pool, c);
        scan4g(v3, p3, tid, pool, c);
    }

    // ---- Expand captured groups into the candidate list ----
    uint32_t cc = (c > (uint32_t)NSLOT) ? (uint32_t)NSLOT : c;
    if (c > (uint32_t)NSLOT) ctrl[8] = 1u;        // slot overflow -> fallback
    uint32_t my[NSLOT];
    #pragma unroll
    for (int s = 0; s < NSLOT; ++s) my[s] = pool[s * NT + tid];  // own slots only

    #pragma unroll
    for (int s = 0; s < NSLOT; ++s) {
        if ((uint32_t)s < cc) {
            uint32_t p4 = my[s];
            float4 v = xin[p4];                   // 16B gather, L2/L3-hit mostly
            float fa[4] = {v.x, v.y, v.z, v.w};
            #pragma unroll
            for (int q = 0; q < 4; ++q) {
                if (fa[q] >= FCUT) {
                    uint32_t idx = atomicAdd(&ctrl[3], 1u);
                    if (idx < CAP)
                        list[idx] = make_uint2(__float_as_uint(fa[q]),
                                               p4 * 4u + (uint32_t)q);
                    else
                        ctrl[8] = 1u;             // list overflow -> fallback
                }
            }
        }
    }
    __syncthreads();
    const uint32_t M   = ctrl[3];
    const bool     ovf = (ctrl[8] != 0u);

    if (!ovf && M >= KSEL && M <= CAP) {
        // ---- Main path: exact 4x8-bit radix select over M candidates ----
        uint32_t need = KSEL;
        uint32_t pref = 0;
        uint32_t cnt  = 0;
        #pragma unroll
        for (int L = 3; L >= 0; --L) {
            __syncthreads();
            if (tid < 256) hist[tid] = 0u;
            __syncthreads();
            for (uint32_t i = tid; i < M; i += NT) {
                uint32_t u = list[i].x;
                bool inb = (L == 3) || ((u >> ((L + 1) * 8)) == pref);
                if (inb) atomicAdd(&hist[(u >> (L * 8)) & 0xFFu], 1u);
            }
            __syncthreads();
            wave0_select(ctrl, hist, 256, need, tid, lane);
            __syncthreads();
            uint32_t d = ctrl[0], cum = ctrl[1];
            cnt = ctrl[2];
            pref = (pref << 8) | d;
            need = need - cum;        // 1..cnt
        }
        uint32_t T32 = pref;          // exact 64th-largest key (raw bits)
        uint32_t r   = need;          // #(==T32) to include, lowest index first

        // ---- Emit winners to workspace ----
        for (uint32_t i = tid; i < M; i += NT) {
            uint32_t u = list[i].x;
            bool take = false;
            if (u > T32) take = true;
            else if (u == T32) {
                take = (r == cnt);
                if (!take) {
                    uint32_t myp = list[i].y, rank = 0;
                    for (uint32_t j2 = 0; j2 < M; ++j2)
                        rank += (list[j2].x == T32 && list[j2].y < myp);
                    take = (rank < r);
                }
            }
            if (take) {                          // all >= 2.6 > 0, relu no-op
                uint32_t w = atomicAdd(&ctrl[10], 1u);
                wswin[(size_t)row * KSEL + w] = make_uint2(list[i].y, u);
            }
        }
        __syncthreads();
        if (tid == 0) wscnt[row] = ctrl[10];
        return;
    }

    // ---- Fallback: exact 32-bit radix over global re-reads ----
    uint32_t* hist2 = (uint32_t*)list;   // 2048 u32 available

    // Level A: bits 31:21
    for (int i = tid; i < 2048; i += NT) hist2[i] = 0u;
    __syncthreads();
    for (int j = 0; j < ITERS; ++j) {
        float4 v = xin[j * NT + tid];
        uint32_t u[4] = { f2o(__float_as_uint(v.x)), f2o(__float_as_uint(v.y)),
                          f2o(__float_as_uint(v.z)), f2o(__float_as_uint(v.w)) };
        #pragma unroll
        for (int q = 0; q < 4; ++q) atomicAdd(&hist2[u[q] >> 21], 1u);
    }
    __syncthreads();
    wave0_select(ctrl, hist2, 2048, KSEL, tid, lane);
    __syncthreads();
    uint32_t bA = ctrl[0], cumA = ctrl[1];
    uint32_t needB = KSEL - cumA;

    // Level B: bits 20:10 within bucket bA
    __syncthreads();
    for (int i = tid; i < 2048; i += NT) hist2[i] = 0u;
    __syncthreads();
    for (int j = 0; j < ITERS; ++j) {
        float4 v = xin[j * NT + tid];
        uint32_t u[4] = { f2o(__float_as_uint(v.x)), f2o(__float_as_uint(v.y)),
                          f2o(__float_as_uint(v.z)), f2o(__float_as_uint(v.w)) };
        #pragma unroll
        for (int q = 0; q < 4; ++q)
            if ((u[q] >> 21) == bA) atomicAdd(&hist2[(u[q] >> 10) & 0x7FFu], 1u);
    }
    __syncthreads();
    wave0_select(ctrl, hist2, 2048, needB, tid, lane);
    __syncthreads();
    uint32_t bB = ctrl[0], cumB = ctrl[1];
    uint32_t P22 = (bA << 11) | bB;
    uint32_t needC = needB - cumB;

    // Level C: bits 9:0 within prefix P22
    __syncthreads();
    for (int i = tid; i < 2048; i += NT) hist2[i] = 0u;
    __syncthreads();
    for (int j = 0; j < ITERS; ++j) {
        float4 v = xin[j * NT + tid];
        uint32_t u[4] = { f2o(__float_as_uint(v.x)), f2o(__float_as_uint(v.y)),
                          f2o(__float_as_uint(v.z)), f2o(__float_as_uint(v.w)) };
        #pragma unroll
        for (int q = 0; q < 4; ++q)
            if ((u[q] >> 10) == P22) atomicAdd(&hist2[u[q] & 0x3FFu], 1u);
    }
    __syncthreads();
    wave0_select(ctrl, hist2, 1024, needC, tid, lane);
    __syncthreads();
    uint32_t bC = ctrl[0], cumC = ctrl[1];
    uint32_t T32f = (P22 << 10) | bC;
    uint32_t r2   = needC - cumC;    // #(==T32f) to include, lowest index first

    // Ordered rank of ==T32f over contiguous chunks (index order).
    const int cbase = tid * (LROW / NT);
    uint32_t cc2 = 0;
    for (int j = 0; j < LROW / NT; ++j)
        cc2 += (f2o(__float_as_uint(x[rowoff + cbase + j])) == T32f);
    uint32_t inc2 = cc2;
    #pragma unroll
    for (int off = 1; off < 64; off <<= 1) {
        uint32_t t = __shfl_up(inc2, off);
        if (lane >= off) inc2 += t;
    }
    if (lane == 63) ctrl[16 + wid] = inc2;
    __syncthreads();
    if (tid < NWAVE) {
        uint32_t v = ctrl[16 + tid];
        uint32_t i2 = v;
        #pragma unroll
        for (int off = 1; off < NWAVE; off <<= 1) {
            uint32_t t = __shfl_up(i2, off);
            if (lane >= off) i2 += t;
        }
        ctrl[16 + tid] = i2 - v;     // exclusive wave base
    }
    __syncthreads();
    uint32_t rank = ctrl[16 + wid] + (inc2 - cc2);
    for (int j = 0; j < LROW / NT; ++j) {
        uint32_t u = f2o(__float_as_uint(x[rowoff + cbase + j]));
        bool take = false;
        if (u > T32f) take = true;
        else if (u == T32f) { take = (rank < r2); rank++; }
        if (take) {
            float v = o2f(u);
            if (v > 0.f) {           // relu: non-positive winners = background
                uint32_t w = atomicAdd(&ctrl[10], 1u);
                wswin[(size_t)row * KSEL + w] =
                    make_uint2((uint32_t)(cbase + j), __float_as_uint(v));
            }
        }
    }
    __syncthreads();
    if (tid == 0) wscnt[row] = ctrl[10];
}

// ======================== Kernel B: fill + scatter ========================
__global__ __launch_bounds__(NT, 8) void fill_scatter_kernel(
    float* __restrict__ out, const uint2* __restrict__ wswin,
    const uint32_t* __restrict__ wscnt)
{
    const uint32_t row = blockIdx.x;
    const size_t rowoff = (size_t)row * LROW;
    vf4* __restrict__ o4 = (vf4*)(out + rowoff);
    const vf4 z = (vf4)(0.0f);
    #pragma unroll
    for (int j = 0; j < LROW / (NT * 4); ++j)     // 32 NT stores/thread
        __builtin_nontemporal_store(z, &o4[j * NT + threadIdx.x]);
    __syncthreads();                               // vmcnt(0) drain + barrier
    uint32_t n = wscnt[row];
    if (threadIdx.x < n) {
        uint2 w = wswin[(size_t)row * KSEL + threadIdx.x];
        out[rowoff + w.x] = __uint_as_float(w.y);
    }
}

// ================= Fused fallback (R9, proven): ws too small ==============
__global__ __launch_bounds__(NT, 8) void topk_fused(
    const float* __restrict__ x, float* __restrict__ out)
{
    __shared__ uint32_t pool[(NSLOT + 1) * NT];
    __shared__ uint2    list[CAP];
    __shared__ uint32_t hist[256];
    __shared__ uint32_t ctrl[64];

    const int tid  = threadIdx.x;
    const int lane = tid & 63;
    const int wid  = tid >> 6;
    const size_t rowoff = (size_t)blockIdx.x * LROW;
    const float4* __restrict__ xin  = (const float4*)(x + rowoff);
    vf4*          __restrict__ xout = (vf4*)(out + rowoff);

    if (tid == 0) { ctrl[3] = 0u; ctrl[8] = 0u; }
    __syncthreads();

    uint32_t c = 0;
    const vf4 z = (vf4)(0.0f);
    for (int j = 0; j < ITERS; j += 4) {
        int p0 = (j + 0) * NT + tid;
        int p1 = (j + 1) * NT + tid;
        int p2 = (j + 2) * NT + tid;
        int p3 = (j + 3) * NT + tid;
        float4 v0 = xin[p0];
        float4 v1 = xin[p1];
        float4 v2 = xin[p2];
        float4 v3 = xin[p3];
        __builtin_nontemporal_store(z, &xout[p0]);
        __builtin_nontemporal_store(z, &xout[p1]);
        __builtin_nontemporal_store(z, &xout[p2]);
        __builtin_nontemporal_store(z, &xout[p3]);
        scan4g(v0, p0, tid, pool, c);
        scan4g(v1, p1, tid, pool, c);
        scan4g(v2, p2, tid, pool, c);
        scan4g(v3, p3, tid, pool, c);
    }

    uint32_t cc = (c > (uint32_t)NSLOT) ? (uint32_t)NSLOT : c;
    if (c > (uint32_t)NSLOT) ctrl[8] = 1u;
    uint32_t my[NSLOT];
    #pragma unroll
    for (int s = 0; s < NSLOT; ++s) my[s] = pool[s * NT + tid];
    #pragma unroll
    for (int s = 0; s < NSLOT; ++s) {
        if ((uint32_t)s < cc) {
            uint32_t p4 = my[s];
            float4 v = xin[p4];
            float fa[4] = {v.x, v.y, v.z, v.w};
            #pragma unroll
            for (int q = 0; q < 4; ++q) {
                if (fa[q] >= FCUT) {
                    uint32_t idx = atomicAdd(&ctrl[3], 1u);
                    if (idx < CAP)
                        list[idx] = make_uint2(__float_as_uint(fa[q]),
                                               p4 * 4u + (uint32_t)q);
                    else
                        ctrl[8] = 1u;
                }
            }
        }
    }
    __syncthreads();
    const uint32_t M   = ctrl[3];
    const bool     ovf = (ctrl[8] != 0u);

    if (!ovf && M >= KSEL && M <= CAP) {
        uint32_t need = KSEL, pref = 0, cnt = 0;
        #pragma unroll
        for (int L = 3; L >= 0; --L) {
            __syncthreads();
            if (tid < 256) hist[tid] = 0u;
            __syncthreads();
            for (uint32_t i = tid; i < M; i += NT) {
                uint32_t u = list[i].x;
                bool inb = (L == 3) || ((u >> ((L + 1) * 8)) == pref);
                if (inb) atomicAdd(&hist[(u >> (L * 8)) & 0xFFu], 1u);
            }
            __syncthreads();
            wave0_select(ctrl, hist, 256, need, tid, lane);
            __syncthreads();
            uint32_t d = ctrl[0], cum = ctrl[1];
            cnt = ctrl[2];
            pref = (pref << 8) | d;
            need = need - cum;
        }
        uint32_t T32 = pref, r = need;
        for (uint32_t i = tid; i < M; i += NT) {
            uint32_t u = list[i].x;
            if (u > T32) {
                out[rowoff + list[i].y] = __uint_as_float(u);
            } else if (u == T32) {
                bool take = (r == cnt);
                if (!take) {
                    uint32_t myp = list[i].y, rank = 0;
                    for (uint32_t j2 = 0; j2 < M; ++j2)
                        rank += (list[j2].x == T32 && list[j2].y < myp);
                    take = (rank < r);
                }
                if (take) out[rowoff + list[i].y] = __uint_as_float(u);
            }
        }
        return;
    }

    uint32_t* hist2 = (uint32_t*)list;
    for (int i = tid; i < 2048; i += NT) hist2[i] = 0u;
    __syncthreads();
    for (int j = 0; j < ITERS; ++j) {
        float4 v = xin[j * NT + tid];
        uint32_t u[4] = { f2o(__float_as_uint(v.x)), f2o(__float_as_uint(v.y)),
                          f2o(__float_as_uint(v.z)), f2o(__float_as_uint(v.w)) };
        #pragma unroll
        for (int q = 0; q < 4; ++q) atomicAdd(&hist2[u[q] >> 21], 1u);
    }
    __syncthreads();
    wave0_select(ctrl, hist2, 2048, KSEL, tid, lane);
    __syncthreads();
    uint32_t bA = ctrl[0], cumA = ctrl[1];
    uint32_t needB = KSEL - cumA;
    __syncthreads();
    for (int i = tid; i < 2048; i += NT) hist2[i] = 0u;
    __syncthreads();
    for (int j = 0; j < ITERS; ++j) {
        float4 v = xin[j * NT + tid];
        uint32_t u[4] = { f2o(__float_as_uint(v.x)), f2o(__float_as_uint(v.y)),
                          f2o(__float_as_uint(v.z)), f2o(__float_as_uint(v.w)) };
        #pragma unroll
        for (int q = 0; q < 4; ++q)
            if ((u[q] >> 21) == bA) atomicAdd(&hist2[(u[q] >> 10) & 0x7FFu], 1u);
    }
    __syncthreads();
    wave0_select(ctrl, hist2, 2048, needB, tid, lane);
    __syncthreads();
    uint32_t bB = ctrl[0], cumB = ctrl[1];
    uint32_t P22 = (bA << 11) | bB;
    uint32_t needC = needB - cumB;
    __syncthreads();
    for (int i = tid; i < 2048; i += NT) hist2[i] = 0u;
    __syncthreads();
    for (int j = 0; j < ITERS; ++j) {
        float4 v = xin[j * NT + tid];
        uint32_t u[4] = { f2o(__float_as_uint(v.x)), f2o(__float_as_uint(v.y)),
                          f2o(__float_as_uint(v.z)), f2o(__float_as_uint(v.w)) };
        #pragma unroll
        for (int q = 0; q < 4; ++q)
            if ((u[q] >> 10) == P22) atomicAdd(&hist2[u[q] & 0x3FFu], 1u);
    }
    __syncthreads();
    wave0_select(ctrl, hist2, 1024, needC, tid, lane);
    __syncthreads();
    uint32_t bC = ctrl[0], cumC = ctrl[1];
    uint32_t T32f = (P22 << 10) | bC;
    uint32_t r2   = needC - cumC;

    const int cbase = tid * (LROW / NT);
    uint32_t cc2 = 0;
    for (int j = 0; j < LROW / NT; ++j)
        cc2 += (f2o(__float_as_uint(x[rowoff + cbase + j])) == T32f);
    uint32_t inc2 = cc2;
    #pragma unroll
    for (int off = 1; off < 64; off <<= 1) {
        uint32_t t = __shfl_up(inc2, off);
        if (lane >= off) inc2 += t;
    }
    if (lane == 63) ctrl[16 + wid] = inc2;
    __syncthreads();
    if (tid < NWAVE) {
        uint32_t v = ctrl[16 + tid];
        uint32_t i2 = v;
        #pragma unroll
        for (int off = 1; off < NWAVE; off <<= 1) {
            uint32_t t = __shfl_up(i2, off);
            if (lane >= off) i2 += t;
        }
        ctrl[16 + tid] = i2 - v;
    }
    __syncthreads();
    uint32_t rank = ctrl[16 + wid] + (inc2 - cc2);
    for (int j = 0; j < LROW / NT; ++j) {
        uint32_t u = f2o(__float_as_uint(x[rowoff + cbase + j]));
        bool take = false;
        if (u > T32f) take = true;
        else if (u == T32f) { take = (rank < r2); rank++; }
        if (take) {
            float v = o2f(u);
            if (v > 0.f) out[rowoff + cbase + j] = v;
        }
    }
}

extern "C" void kernel_launch(void* const* d_in, const int* in_sizes, int n_in,
                              void* d_out, int out_size, void* d_ws, size_t ws_size,
                              hipStream_t stream)
{
    const float* x = (const float*)d_in[0];
    float* out = (float*)d_out;
    int rows = in_sizes[0] / LROW;   // 4096

    size_t need_ws = (size_t)rows * KSEL * sizeof(uint2)   // winners
                   + (size_t)rows * sizeof(uint32_t);      // counts
    if (ws_size >= need_ws) {
        uint2*    wswin = (uint2*)d_ws;
        uint32_t* wscnt = (uint32_t*)((char*)d_ws + (size_t)rows * KSEL * sizeof(uint2));
        select_kernel<<<rows, NT, 0, stream>>>(x, wswin, wscnt);
        fill_scatter_kernel<<<rows, NT, 0, stream>>>(out, wswin, wscnt);
    } else {
        topk_fused<<<rows, NT, 0, stream>>>(x, out);
    }
}

// Round 11
// 231.829 us; speedup vs baseline: 1.0345x; 1.0345x over previous
//
#include <hip/hip_runtime.h>
#include <stdint.h>

// Top-K (K=64) per row of [4096, 32768] f32, relu'd, scattered into zeros.
//
// Round-11: fused stream (proven, ~copy-speed) + MINIMAL tail.
//   Model from R8/R9/R10: total = stream(~170us) + 16 rows/CU x tail, where
//   the tail does NOT overlap across blocks (all resident blocks hit it
//   simultaneously - lockstep progress under equal BW share). R9's tail
//   (4-level radix select, ~16 barriers) ~ 3-4us/row -> ~50us of the 223.
//  - Capture (R8, branchless): each thread owns 8 LDS uint2 slots + trash;
//    per element an UNCONDITIONAL ds_write_b64 {key,pos} to slot min(c,8),
//    c += (f >= 2.6f). No branch/atomic/wait in the hot loop.
//  - Tail (new): compact slots into a list (shfl prefix scan, 2 barriers),
//    then BRUTE-FORCE RANK: for candidate i, rank = #{key_j > key_i} +
//    #{key_j==key_i && pos_j<pos_i} via one M~153-iteration LDS-broadcast
//    loop (no barriers, all waves parallel). take = rank < 64. Exact
//    jax.lax.top_k semantics by construction. ~1us total.
//  - M <= 256*8 = 2048 structurally; fallback only on slot overflow or
//    M < 64 (statistically never): exact 32-bit radix over global re-reads,
//    ordered tie-break, explicit relu. Exact for ANY input.

#define LROW   32768
#define NT     256
#define NWAVE  (NT / 64)            // 4
#define ITERS  (LROW / (NT * 4))    // 32
#define KSEL   64u
#define NSLOT  8                    // {key,pos} slots per thread (+1 trash)
#define FCUT   2.6f                 // candidate threshold (value space)

typedef float vf4 __attribute__((ext_vector_type(4)));

// float bits -> order-preserving uint (used only in the fallback)
__device__ __forceinline__ uint32_t f2o(uint32_t b) {
    return b ^ (uint32_t)(((int32_t)b >> 31) | 0x80000000u);
}
__device__ __forceinline__ float o2f(uint32_t u) {
    uint32_t b = (u & 0x80000000u) ? (u ^ 0x80000000u) : ~u;
    return __uint_as_float(b);
}

// Fallback-only: wave 0 scans hist[nb-1..0] from the top; finds bucket b*
// with cum_before < need <= cum_before + hist[b*]; writes
// {b*, cum_before, hist[b*]} to ctrl[0..2].
__device__ __forceinline__ void wave0_select(uint32_t* ctrl, const uint32_t* hist,
                                             int nb, uint32_t need,
                                             int tid, int lane)
{
    if (tid < 64) {
        uint32_t cum = 0;
        int done = 0;
        for (int base = nb; base > 0 && !done; base -= 64) {
            uint32_t c = hist[base - 1 - lane];   // lane 0 = highest bucket
            uint32_t inc = c;
            #pragma unroll
            for (int off = 1; off < 64; off <<= 1) {
                uint32_t t = __shfl_up(inc, off);
                if (lane >= off) inc += t;
            }
            uint32_t tot = __shfl(inc, 63);
            uint32_t pre = inc - c;
            bool hit = (cum + pre < need) && (cum + pre + c >= need);
            if (hit) {
                ctrl[0] = (uint32_t)(base - 1 - lane);
                ctrl[1] = cum + pre;
                ctrl[2] = c;
            }
            done = (__ballot(hit) != 0ull);
            cum += tot;
        }
    }
}

// Branchless per-element capture: unconditional slot write + cndmask bump.
__device__ __forceinline__ void scan4(const float4& v, int p4, int tid,
                                      uint2* pool, uint32_t& c)
{
    const float f0 = v.x, f1 = v.y, f2 = v.z, f3 = v.w;
    uint32_t s;
    s = (c > (uint32_t)NSLOT) ? (uint32_t)NSLOT : c;
    pool[s * NT + tid] = make_uint2(__float_as_uint(f0), (uint32_t)(p4 * 4 + 0));
    c += (f0 >= FCUT) ? 1u : 0u;
    s = (c > (uint32_t)NSLOT) ? (uint32_t)NSLOT : c;
    pool[s * NT + tid] = make_uint2(__float_as_uint(f1), (uint32_t)(p4 * 4 + 1));
    c += (f1 >= FCUT) ? 1u : 0u;
    s = (c > (uint32_t)NSLOT) ? (uint32_t)NSLOT : c;
    pool[s * NT + tid] = make_uint2(__float_as_uint(f2), (uint32_t)(p4 * 4 + 2));
    c += (f2 >= FCUT) ? 1u : 0u;
    s = (c > (uint32_t)NSLOT) ? (uint32_t)NSLOT : c;
    pool[s * NT + tid] = make_uint2(__float_as_uint(f3), (uint32_t)(p4 * 4 + 3));
    c += (f3 >= FCUT) ? 1u : 0u;
}

__global__ __launch_bounds__(NT, 8) void topk_kernel(
    const float* __restrict__ x, float* __restrict__ out)
{
    // pool: slot view [NSLOT+1][NT] during stream; compacted list + fallback
    // histogram afterwards. (NSLOT+1)*NT uint2 = 18 KiB.
    __shared__ uint2    pool[(NSLOT + 1) * NT];
    __shared__ uint32_t ctrl[64];   // [0..2] fb-select, [8] ovf, [9] M, [16..] wave sums

    const int tid  = threadIdx.x;
    const int lane = tid & 63;
    const int wid  = tid >> 6;
    const size_t rowoff = (size_t)blockIdx.x * LROW;
    const float4* __restrict__ xin  = (const float4*)(x + rowoff);
    vf4*          __restrict__ xout = (vf4*)(out + rowoff);

    if (tid == 0) ctrl[8] = 0u;
    __syncthreads();

    // ---- Phase 0: fused stream: 4 loads | 4 NT zero-stores | capture ----
    uint32_t c = 0;
    const vf4 z = (vf4)(0.0f);
    for (int j = 0; j < ITERS; j += 4) {
        int p0 = (j + 0) * NT + tid;
        int p1 = (j + 1) * NT + tid;
        int p2 = (j + 2) * NT + tid;
        int p3 = (j + 3) * NT + tid;
        float4 v0 = xin[p0];
        float4 v1 = xin[p1];
        float4 v2 = xin[p2];
        float4 v3 = xin[p3];
        __builtin_nontemporal_store(z, &xout[p0]);
        __builtin_nontemporal_store(z, &xout[p1]);
        __builtin_nontemporal_store(z, &xout[p2]);
        __builtin_nontemporal_store(z, &xout[p3]);
        scan4(v0, p0, tid, pool, c);
        scan4(v1, p1, tid, pool, c);
        scan4(v2, p2, tid, pool, c);
        scan4(v3, p3, tid, pool, c);
    }

    // ---- Compact per-thread slots into one list (3 barriers total) ----
    uint32_t cc = (c > (uint32_t)NSLOT) ? (uint32_t)NSLOT : c;
    uint2 mine[NSLOT];
    #pragma unroll
    for (int s = 0; s < NSLOT; ++s) mine[s] = pool[s * NT + tid];  // own slots

    uint32_t inc = cc;
    #pragma unroll
    for (int off = 1; off < 64; off <<= 1) {
        uint32_t t = __shfl_up(inc, off);
        if (lane >= off) inc += t;
    }
    if (lane == 63) ctrl[16 + wid] = inc;
    if (__any(c > (uint32_t)NSLOT) && lane == 0) ctrl[8] = 1u;  // overflow
    __syncthreads();                                   // B1: reads done, sums in
    if (tid < NWAVE) {
        uint32_t v = ctrl[16 + tid];
        uint32_t i2 = v;
        #pragma unroll
        for (int off = 1; off < NWAVE; off <<= 1) {
            uint32_t t = __shfl_up(i2, off);
            if (lane >= off) i2 += t;
        }
        if (tid == NWAVE - 1) ctrl[9] = i2;            // total M
        ctrl[16 + tid] = i2 - v;                       // exclusive wave base
    }
    __syncthreads();                                   // B2
    const uint32_t M   = ctrl[9];
    const bool     ovf = (ctrl[8] != 0u);
    uint32_t ofs = ctrl[16 + wid] + (inc - cc);
    #pragma unroll
    for (int s = 0; s < NSLOT; ++s)
        if ((uint32_t)s < cc) pool[ofs + s] = mine[s];
    __syncthreads();                                   // B3: list ready

    if (!ovf && M >= KSEL) {                           // M <= 2048 structurally
        // ---- Brute-force exact rank (no barriers, all waves parallel) ----
        // rank(i) = #{key_j > key_i} + #{key_j == key_i && pos_j < pos_i};
        // take iff rank < KSEL. Exact jax.lax.top_k (lowest-index ties).
        for (uint32_t i = tid; i < M; i += NT) {
            uint2 me = pool[i];
            uint32_t rank = 0;
            for (uint32_t j2 = 0; j2 < M; ++j2) {
                uint2 oth = pool[j2];                  // LDS broadcast read
                rank += (oth.x > me.x) ||
                        (oth.x == me.x && oth.y < me.y);
            }
            if (rank < KSEL)
                out[rowoff + me.y] = __uint_as_float(me.x);  // >= 2.6 > 0
        }
        return;
    }

    // ---- Fallback: exact 32-bit radix over global re-reads (correctness
    //      insurance; statistically never taken for N(0,1) rows) ----
    uint32_t* hist2 = (uint32_t*)pool;   // 2048-entry histogram (4608 u32 avail)

    // Level A: bits 31:21
    for (int i = tid; i < 2048; i += NT) hist2[i] = 0u;
    __syncthreads();
    for (int j = 0; j < ITERS; ++j) {
        float4 v = xin[j * NT + tid];
        uint32_t u[4] = { f2o(__float_as_uint(v.x)), f2o(__float_as_uint(v.y)),
                          f2o(__float_as_uint(v.z)), f2o(__float_as_uint(v.w)) };
        #pragma unroll
        for (int q = 0; q < 4; ++q) atomicAdd(&hist2[u[q] >> 21], 1u);
    }
    __syncthreads();
    wave0_select(ctrl, hist2, 2048, KSEL, tid, lane);
    __syncthreads();
    uint32_t bA = ctrl[0], cumA = ctrl[1];
    uint32_t needB = KSEL - cumA;

    // Level B: bits 20:10 within bucket bA
    __syncthreads();
    for (int i = tid; i < 2048; i += NT) hist2[i] = 0u;
    __syncthreads();
    for (int j = 0; j < ITERS; ++j) {
        float4 v = xin[j * NT + tid];
        uint32_t u[4] = { f2o(__float_as_uint(v.x)), f2o(__float_as_uint(v.y)),
                          f2o(__float_as_uint(v.z)), f2o(__float_as_uint(v.w)) };
        #pragma unroll
        for (int q = 0; q < 4; ++q)
            if ((u[q] >> 21) == bA) atomicAdd(&hist2[(u[q] >> 10) & 0x7FFu], 1u);
    }
    __syncthreads();
    wave0_select(ctrl, hist2, 2048, needB, tid, lane);
    __syncthreads();
    uint32_t bB = ctrl[0], cumB = ctrl[1];
    uint32_t P22 = (bA << 11) | bB;
    uint32_t needC = needB - cumB;

    // Level C: bits 9:0 within prefix P22
    __syncthreads();
    for (int i = tid; i < 2048; i += NT) hist2[i] = 0u;
    __syncthreads();
    for (int j = 0; j < ITERS; ++j) {
        float4 v = xin[j * NT + tid];
        uint32_t u[4] = { f2o(__float_as_uint(v.x)), f2o(__float_as_uint(v.y)),
                          f2o(__float_as_uint(v.z)), f2o(__float_as_uint(v.w)) };
        #pragma unroll
        for (int q = 0; q < 4; ++q)
            if ((u[q] >> 10) == P22) atomicAdd(&hist2[u[q] & 0x3FFu], 1u);
    }
    __syncthreads();
    wave0_select(ctrl, hist2, 1024, needC, tid, lane);
    __syncthreads();
    uint32_t bC = ctrl[0], cumC = ctrl[1];
    uint32_t T32f = (P22 << 10) | bC;
    uint32_t r2   = needC - cumC;    // #(==T32f) to include, lowest index first

    // Ordered rank of ==T32f over contiguous chunks (index order), then scatter.
    const int cbase = tid * (LROW / NT);
    uint32_t cc2 = 0;
    for (int j = 0; j < LROW / NT; ++j)
        cc2 += (f2o(__float_as_uint(x[rowoff + cbase + j])) == T32f);
    uint32_t inc2 = cc2;
    #pragma unroll
    for (int off = 1; off < 64; off <<= 1) {
        uint32_t t = __shfl_up(inc2, off);
        if (lane >= off) inc2 += t;
    }
    if (lane == 63) ctrl[16 + wid] = inc2;
    __syncthreads();
    if (tid < NWAVE) {
        uint32_t v = ctrl[16 + tid];
        uint32_t i2 = v;
        #pragma unroll
        for (int off = 1; off < NWAVE; off <<= 1) {
            uint32_t t = __shfl_up(i2, off);
            if (lane >= off) i2 += t;
        }
        ctrl[16 + tid] = i2 - v;     // exclusive wave base
    }
    __syncthreads();
    uint32_t rank = ctrl[16 + wid] + (inc2 - cc2);
    for (int j = 0; j < LROW / NT; ++j) {
        uint32_t u = f2o(__float_as_uint(x[rowoff + cbase + j]));
        bool take = false;
        if (u > T32f) take = true;
        else if (u == T32f) { take = (rank < r2); rank++; }
        if (take) {
            float v = o2f(u);
            if (v > 0.f) out[rowoff + cbase + j] = v;   // relu; 0 == background
        }
    }
}

extern "C" void kernel_launch(void* const* d_in, const int* in_sizes, int n_in,
                              void* d_out, int out_size, void* d_ws, size_t ws_size,
                              hipStream_t stream)
{
    const float* x = (const float*)d_in[0];
    float* out = (float*)d_out;
    int rows = in_sizes[0] / LROW;   // 4096

    topk_kernel<<<rows, NT, 0, stream>>>(x, out);
}